// Round 7
// baseline (14.797 us; speedup 1.0000x reference)
//
#include <hip/hip_runtime.h>
#include <math.h>

#define TM1 127

typedef _Float16 f16x4 __attribute__((ext_vector_type(4)));
typedef float f32x4 __attribute__((ext_vector_type(4)));

__device__ __forceinline__ float lrelu(float v) { return fmaxf(v, 0.01f * v); }

__global__ __launch_bounds__(256, 4) void gat_kernel(
    const float* __restrict__ x,       // (8,64,128,8)
    const float* __restrict__ W_sp,    // (24,64)
    const float* __restrict__ b_sp,    // (64)
    const float* __restrict__ W_node,  // (8,64)
    const float* __restrict__ b_node,  // (64)
    const float* __restrict__ W_att,   // (64,1)
    const float* __restrict__ b_att,   // (1)
    float* __restrict__ out)           // (8,127,64,64)
{
    const int bt = blockIdx.x;
    const int b = bt / TM1;
    const int t = bt - b * TM1;
    const int tid = threadIdx.x;
    const int lane = tid & 63;
    const int wid = tid >> 6;
    const int i = lane & 15;
    const int g = lane >> 4;
    const int g4 = g * 4;

    __shared__ __align__(16) float u_sh[64];
    __shared__ __align__(16) float v_sh[64];   // u + w + b_att
    __shared__ float red[20];                  // p[0..7], q[0..7], c0, c1

    const float wa = W_att[lane];

    // ---- wave0: per-lane x gather for u/w (t,t+1 rows = 16 contiguous floats) ----
    f32x4 xa0, xa1, xd0, xd1;
    if (wid == 0) {
        const float* xr = x + ((b * 64 + lane) * 128 + t) * 8;
        xa0 = *(const f32x4*)(xr);
        xa1 = *(const f32x4*)(xr + 4);
        xd0 = *(const f32x4*)(xr + 8);
        xd1 = *(const f32x4*)(xr + 12);
    }

    // ---- ne-MFMA operand loads: A = x_t rows (f16), B = W_node cols (f16) ----
    // A-frag (16x16x16): lane(i,g) holds A[row=i][k=g4+e]; k=8..15 zero-padded.
    f16x4 xf[4], wf[4];
    if (g < 2) {
#pragma unroll
        for (int s4 = 0; s4 < 4; ++s4) {
            const float* p = x + ((b * 64 + s4 * 16 + i) * 128 + t) * 8 + g4;
            f32x4 v = *(const f32x4*)p;
            f16x4 h;
#pragma unroll
            for (int e = 0; e < 4; ++e) h[e] = (_Float16)v[e];
            xf[s4] = h;
        }
#pragma unroll
        for (int c = 0; c < 4; ++c) {
            f16x4 h;
#pragma unroll
            for (int e = 0; e < 4; ++e) h[e] = (_Float16)W_node[(g4 + e) * 64 + c * 16 + i];
            wf[c] = h;
        }
    } else {
#pragma unroll
        for (int s4 = 0; s4 < 4; ++s4) {
            f16x4 z;
#pragma unroll
            for (int e = 0; e < 4; ++e) z[e] = (_Float16)0.0f;
            xf[s4] = z; wf[s4] = z;
        }
    }

    // ---- split reduction: wave w reduces values 5w..5w+4 of 18 ----
    {
        const int v0 = wid * 5;
        float pr[5];
#pragma unroll
        for (int j = 0; j < 5; ++j) {
            int v = v0 + j;
            float val;
            if (v < 8)        val = W_node[v * 64 + lane] * wa;                              // p[v]
            else if (v < 16)  val = (W_sp[v * 64 + lane] + W_sp[(v + 8) * 64 + lane]) * wa;  // q[v-8]
            else if (v == 16) val = b_sp[lane] * wa;                                         // c0
            else              val = b_node[lane] * wa;                                       // c1
            pr[j] = val;
        }
#pragma unroll
        for (int j = 0; j < 5; ++j) {
            float vv = pr[j];
#pragma unroll
            for (int off = 1; off < 64; off <<= 1) vv += __shfl_xor(vv, off, 64);
            pr[j] = vv;
        }
        if (lane == 0) {
#pragma unroll
            for (int j = 0; j < 5; ++j) {
                int v = v0 + j;
                if (v < 18) red[v] = pr[j];
            }
        }
    }

    // ---- ne = x_t @ W_node (no bias) via 16 MFMAs; D-frags ARE phase-C B-frags ----
    // D[row=s4*16+g4+r][col=c*16+i] = ne[f][d]; element r <-> k-slot e.
    f16x4 B16[4][4];   // [c][s4]
#pragma unroll
    for (int c = 0; c < 4; ++c) {
#pragma unroll
        for (int s4 = 0; s4 < 4; ++s4) {
            f32x4 d = __builtin_amdgcn_mfma_f32_16x16x16f16(
                xf[s4], wf[c], (f32x4){0.f, 0.f, 0.f, 0.f}, 0, 0, 0);
            f16x4 h;
#pragma unroll
            for (int e = 0; e < 4; ++e) h[e] = (_Float16)d[e];
            B16[c][s4] = h;
        }
    }
    __syncthreads();   // B1: red[] published

    // ---- wave0: u[n], v[n] = u+w+b_att ----
    if (wid == 0) {
        float su = 0.f, sw = 0.f;
#pragma unroll
        for (int e = 0; e < 4; ++e) {
            su += xa0[e] * red[e] + xa1[e] * red[4 + e];
            sw += (xd0[e] - xa0[e]) * red[8 + e] + (xd1[e] - xa1[e]) * red[12 + e];
        }
        float u = su + red[17];
        u_sh[lane] = u;
        v_sh[lane] = u + sw + red[16] + b_att[0];
    }
    __syncthreads();   // B2

    // ---- phase C: scores + softmax in registers, MFMA, store ----
    {
        const int n = wid * 16 + i;          // this lane's attention row
        const float un = u_sh[n];

        float a[16];
#pragma unroll
        for (int s4 = 0; s4 < 4; ++s4) {
            f32x4 vf = *(const f32x4*)&v_sh[s4 * 16 + g4];
#pragma unroll
            for (int e = 0; e < 4; ++e) {
                float q = un + vf[e];
                float v = lrelu(q);
                a[s4 * 4 + e] = (s4 * 16 + g4 + e == n) ? 0.0f : v;
            }
        }
        // row softmax: row n lives in lanes {i, i+16, i+32, i+48}
        float m = a[0];
#pragma unroll
        for (int j = 1; j < 16; ++j) m = fmaxf(m, a[j]);
        m = fmaxf(m, __shfl_xor(m, 16, 64));
        m = fmaxf(m, __shfl_xor(m, 32, 64));
        float s = 0.f;
#pragma unroll
        for (int j = 0; j < 16; ++j) {
            float e = __expf(a[j] - m);
            a[j] = e;
            s += e;
        }
        s += __shfl_xor(s, 16, 64);
        s += __shfl_xor(s, 32, 64);
        const float inv = 1.0f / s;

        f16x4 Ah[4];
#pragma unroll
        for (int s4 = 0; s4 < 4; ++s4)
#pragma unroll
            for (int e = 0; e < 4; ++e)
                Ah[s4][e] = (_Float16)(a[s4 * 4 + e] * inv);

        f32x4 acc[4];
#pragma unroll
        for (int c = 0; c < 4; ++c) acc[c] = (f32x4){0.f, 0.f, 0.f, 0.f};
#pragma unroll
        for (int c = 0; c < 4; ++c)
#pragma unroll
            for (int s4 = 0; s4 < 4; ++s4)
                acc[c] = __builtin_amdgcn_mfma_f32_16x16x16f16(Ah[s4], B16[c][s4], acc[c], 0, 0, 0);

        // bias folded through softmax (rows sum to 1): out = acc + b_node[d]
        float bn[4];
#pragma unroll
        for (int c = 0; c < 4; ++c) bn[c] = b_node[c * 16 + i];

        float* op = out + ((long)(b * TM1 + t) << 12);
#pragma unroll
        for (int c = 0; c < 4; ++c) {
#pragma unroll
            for (int r = 0; r < 4; ++r) {
                int row = wid * 16 + g4 + r;     // C/D: row = 4*(lane>>4)+reg
                op[row * 64 + c * 16 + i] = lrelu(acc[c][r] + bn[c]);
            }
        }
    }
}

extern "C" void kernel_launch(void* const* d_in, const int* in_sizes, int n_in,
                              void* d_out, int out_size, void* d_ws, size_t ws_size,
                              hipStream_t stream) {
    const float* x      = (const float*)d_in[0];
    // d_in[1]=rel_rec, d_in[2]=rel_send: one-hot edge matrices, replaced by index math
    const float* W_sp   = (const float*)d_in[3];
    const float* b_sp   = (const float*)d_in[4];
    const float* W_node = (const float*)d_in[5];
    const float* b_node = (const float*)d_in[6];
    const float* W_att  = (const float*)d_in[7];
    const float* b_att  = (const float*)d_in[8];
    float* out = (float*)d_out;

    dim3 grid(8 * TM1);
    dim3 block(256);
    hipLaunchKernelGGL(gat_kernel, grid, block, 0, stream,
                       x, W_sp, b_sp, W_node, b_node, W_att, b_att, out);
}